// Round 6
// baseline (5175.912 us; speedup 1.0000x reference)
//
#include <hip/hip_runtime.h>
#include <hip/hip_bf16.h>

// ---------- types ----------
typedef __attribute__((ext_vector_type(8))) short short8;   // 8 bf16 = 4 VGPRs (MFMA A/B frag)
typedef __attribute__((ext_vector_type(4))) short short4_t; // 4 bf16
typedef __attribute__((ext_vector_type(4))) float f32x4;    // MFMA C/D frag

__device__ __forceinline__ short f2bf(float x) {
  unsigned int u = __builtin_bit_cast(unsigned int, x);
  unsigned int r = (u + 0x7fffu + ((u >> 16) & 1u)) >> 16;
  return (short)r;
}
__device__ __forceinline__ float bf2f(unsigned short u) {
  unsigned int i = ((unsigned int)u) << 16;
  return __builtin_bit_cast(float, i);
}

// packed f32x2 -> bf16x2 as an int (hardware cvt if available; safe fallback)
__device__ __forceinline__ int pkcvt(float a, float b) {
#if __has_builtin(__builtin_amdgcn_cvt_pk_bf16_f32)
  typedef __attribute__((ext_vector_type(2))) __bf16 bf16x2_t;
  bf16x2_t r = __builtin_amdgcn_cvt_pk_bf16_f32(a, b);
  return __builtin_bit_cast(int, r);
#else
  unsigned int lo = (unsigned short)f2bf(a);
  unsigned int hi = (unsigned short)f2bf(b);
  return (int)(lo | (hi << 16));
#endif
}

#define HROW 520    // shorts per LDS row (1040 B: 16B-aligned, 2-way bank alias = free)

// lgkmcnt-only barrier (no vmcnt drain)
#define LDS_BARRIER() asm volatile("s_waitcnt lgkmcnt(0)\n\ts_barrier" ::: "memory")

// ---------- kernel W: convert Wh fp32 -> bf16 ----------
__global__ __launch_bounds__(256) void kcvt(const float* __restrict__ Wh,
                                            short* __restrict__ Whb) {
  int i = blockIdx.x * 256 + threadIdx.x;          // 65536 float4 groups
  float4 v = ((const float4*)Wh)[i];
  short4_t o;
  o[0] = f2bf(v.x); o[1] = f2bf(v.y); o[2] = f2bf(v.z); o[3] = f2bf(v.w);
  ((short4_t*)Whb)[i] = o;
}

// ---------- kernel A: xp[s][b][h] = sum_e emb[ids[b][s]][e]*Wi[h][e] + bi[h] + bh[h] (bf16) ----------
__global__ __launch_bounds__(256) void kxproj(const int* __restrict__ ids,    // [B=64][S=512]
                                              const float* __restrict__ emb,  // [V][256]
                                              const float* __restrict__ Wi,   // [512][256]
                                              const float* __restrict__ bi,   // [512]
                                              const float* __restrict__ bh,   // [512]
                                              short* __restrict__ xp) {       // [S][64][512] bf16
  const int s  = blockIdx.x;       // 0..511
  const int hb = blockIdx.y;       // 0..1  (h-block of 256)
  __shared__ __align__(16) char smem[42240];
  float* emb_t = (float*)smem;              // [32][68]  = 8704 B
  float* wi_t  = (float*)(smem + 8704);     // [32][260] = 33280 B
  short* stage = (short*)smem;              // [64][264] = 33792 B (phase 2)
  __shared__ int ids_s[64];
  const int tid = threadIdx.x;
  const int b0 = (tid & 7) * 8;
  const int h0 = (tid >> 3) * 8;

  if (tid < 64) ids_s[tid] = ids[tid * 512 + s];
  __syncthreads();

  float acc[8][8];
  #pragma unroll
  for (int i = 0; i < 8; ++i)
    #pragma unroll
    for (int j = 0; j < 8; ++j) acc[i][j] = 0.f;

  for (int ec = 0; ec < 256; ec += 32) {
    #pragma unroll
    for (int j = 0; j < 8; ++j) {
      int idx = j * 256 + tid;
      int e = idx & 31, b = idx >> 5;
      emb_t[e * 68 + b] = emb[ids_s[b] * 256 + ec + e];
    }
    #pragma unroll
    for (int j = 0; j < 8; ++j) {
      int idx4 = j * 256 + tid;
      int e4 = (idx4 & 7) * 4, hl = idx4 >> 3;
      float4 f = *(const float4*)&Wi[(hb * 256 + hl) * 256 + ec + e4];
      wi_t[(e4 + 0) * 260 + hl] = f.x;
      wi_t[(e4 + 1) * 260 + hl] = f.y;
      wi_t[(e4 + 2) * 260 + hl] = f.z;
      wi_t[(e4 + 3) * 260 + hl] = f.w;
    }
    __syncthreads();
    for (int e = 0; e < 32; ++e) {
      const float4 eb0 = *(const float4*)&emb_t[e * 68 + b0];
      const float4 eb1 = *(const float4*)&emb_t[e * 68 + b0 + 4];
      const float4 w0  = *(const float4*)&wi_t[e * 260 + h0];
      const float4 w1  = *(const float4*)&wi_t[e * 260 + h0 + 4];
      float av[8] = {eb0.x, eb0.y, eb0.z, eb0.w, eb1.x, eb1.y, eb1.z, eb1.w};
      float wv[8] = {w0.x, w0.y, w0.z, w0.w, w1.x, w1.y, w1.z, w1.w};
      #pragma unroll
      for (int i = 0; i < 8; ++i)
        #pragma unroll
        for (int j = 0; j < 8; ++j) acc[i][j] += av[i] * wv[j];
    }
    __syncthreads();
  }
  float add[8];
  #pragma unroll
  for (int hj = 0; hj < 8; ++hj) { int h = hb * 256 + h0 + hj; add[hj] = bi[h] + bh[h]; }
  #pragma unroll
  for (int b2 = 0; b2 < 8; ++b2) {
    short8 pk;
    #pragma unroll
    for (int hj = 0; hj < 8; ++hj) pk[hj] = f2bf(acc[b2][hj] + add[hj]);
    *(short8*)&stage[(b0 + b2) * 264 + h0] = pk;
  }
  __syncthreads();
  {
    int n = tid >> 2, ch = tid & 3;
    const short* src = &stage[n * 264 + ch * 64];
    short* dst = &xp[((size_t)s * 64 + n) * 512 + hb * 256 + ch * 64];
    #pragma unroll
    for (int j = 0; j < 8; ++j) *(short8*)&dst[j * 8] = *(const short8*)&src[j * 8];
  }
}

// ---------- kernel B: the recurrence. 4 groups x 2 CUs (M-split), 8 waves each. ----------
// Block b: active iff (b & 4) == 0. g = b & 3 (batch group), p = (b>>3)&1 (M half).
// Pairing (g, g+8) keeps a pair on one XCD under %8 round-robin (perf heuristic only).
// Each CU: M = 256 rows, wave w owns rows [p*256 + 32w, +32): 2 register A-tiles
// (128 VGPRs) — NO LDS A-tile reads in the loop. h state (16 batches x 512 bf16)
// in LDS. Per step: own-half-K MFMAs first (local h), then receive partner half
// via device-scope flag + ping-pong exchange buffer in d_out, then partner-half
// MFMAs, epilogue, post own half + release flag.
__global__ __launch_bounds__(512, 2) void krnn(const short* __restrict__ Whb, // [512][512] bf16
                                               short* xp,      // [S][64][512] bf16; first 128 KB reused as hid (fp32) at s=511
                                               int* flags,     // d_out[0..64): flag[cu] at int offset cu*8
                                               short* exch) {  // d_out+64: [2 parity][8 cu][16 n][256 k] bf16
  __shared__ short h_lds[16 * HROW];   // 16,640 B
  const int blk = blockIdx.x;
  if (blk & 4) return;                 // spacer blocks (XCD pairing trick)
  const int g   = blk & 3;
  const int p   = (blk >> 3) & 1;
  const int cu  = p * 4 + g;
  const int pcu = (1 - p) * 4 + g;
  const int tid = threadIdx.x;
  const int w   = tid >> 6;       // wave 0..7
  const int l   = tid & 63;
  const int n   = l & 15;         // MFMA col (batch) / A-row-in-tile
  const int q   = l >> 4;         // quad 0..3
  const int m0  = p * 256 + w * 32;   // this wave's first output row
  const int own0 = p * 8;             // own kt range [own0, own0+8)
  const int pkt0 = 8 - p * 8;         // partner kt range
  const int pk0  = 256 - p * 256;     // partner k base (shorts)

  float* hid = (float*)xp;            // final hidden (fp32) — xp rows 0..1, consumed long before s=511

  for (int i = tid; i < 16 * HROW / 2; i += 512) ((int*)h_lds)[i] = 0;

  // register A-frags, 2 tiles: A[m = n][k = q*8+j]
  short8 areg[2][16];
  #pragma unroll
  for (int t = 0; t < 2; ++t) {
    const short* base = &Whb[(m0 + t * 16 + n) * 512 + q * 8];
    #pragma unroll
    for (int kt = 0; kt < 16; ++kt) areg[t][kt] = *(const short8*)&base[kt * 32];
  }
  __syncthreads();

  const short* xrow = &xp[(size_t)(g * 16 + n) * 512 + m0];
  short4_t xv[2];
  #pragma unroll
  for (int t = 0; t < 2; ++t) xv[t] = *(const short4_t*)&xrow[t * 16 + q * 4];

  const int pidx = w * 64 + l;        // 0..511 — partner-half copy assignment
  const int pn = pidx >> 5, pc = pidx & 31;

  for (int s = 0; s < 512; ++s) {
    f32x4 acc0 = {0.f, 0.f, 0.f, 0.f}, acc1 = acc0;

    // phase 1: own-half K (h values this CU computed last step — already in LDS)
    #pragma unroll
    for (int j = 0; j < 8; ++j) {
      int kt = own0 + j;
      short8 bfrag = *(const short8*)&h_lds[n * HROW + kt * 32 + q * 8];
      acc0 = __builtin_amdgcn_mfma_f32_16x16x32_bf16(areg[0][kt], bfrag, acc0, 0, 0, 0);
      acc1 = __builtin_amdgcn_mfma_f32_16x16x32_bf16(areg[1][kt], bfrag, acc1, 0, 0, 0);
    }

    // phase 2: receive partner half of h_s (skip s=0: h0 = 0 everywhere)
    if (s > 0) {
      while (__hip_atomic_load(&flags[pcu * 8], __ATOMIC_RELAXED,
                               __HIP_MEMORY_SCOPE_AGENT) < s) {}
      (void)__hip_atomic_load(&flags[pcu * 8], __ATOMIC_ACQUIRE,
                              __HIP_MEMORY_SCOPE_AGENT);
      const short* src = &exch[((size_t)((s & 1) * 8 + pcu)) * 4096 + pn * 256 + pc * 8];
      short8 v = *(const short8*)src;
      *(short8*)&h_lds[pn * HROW + pk0 + pc * 8] = v;
      LDS_BARRIER();
    }

    // phase 3: partner-half K
    #pragma unroll
    for (int j = 0; j < 8; ++j) {
      int kt = pkt0 + j;
      short8 bfrag = *(const short8*)&h_lds[n * HROW + kt * 32 + q * 8];
      acc0 = __builtin_amdgcn_mfma_f32_16x16x32_bf16(areg[0][kt], bfrag, acc0, 0, 0, 0);
      acc1 = __builtin_amdgcn_mfma_f32_16x16x32_bf16(areg[1][kt], bfrag, acc1, 0, 0, 0);
    }

    // epilogue: z = Wh.h + x, h' = sigmoid(z) for own rows
    #pragma unroll
    for (int t = 0; t < 2; ++t) {
      f32x4 a = t ? acc1 : acc0;
      float hv4[4];
      #pragma unroll
      for (int i = 0; i < 4; ++i) {
        float z = a[i] + bf2f((unsigned short)xv[t][i]);
        float e = __expf(-z);
        hv4[i] = __builtin_amdgcn_rcpf(1.f + e);
      }
      int2 hpk;
      hpk.x = pkcvt(hv4[0], hv4[1]);
      hpk.y = pkcvt(hv4[2], hv4[3]);
      short4_t hh = __builtin_bit_cast(short4_t, hpk);
      *(short4_t*)&h_lds[n * HROW + m0 + t * 16 + q * 4] = hh;       // local own rows
      if (s < 511) {                                                  // post to partner
        *(short4_t*)&exch[((size_t)(((s + 1) & 1) * 8 + cu)) * 4096 +
                          n * 256 + w * 32 + t * 16 + q * 4] = hh;
      } else {                                                        // final hidden
        #pragma unroll
        for (int i = 0; i < 4; ++i)
          hid[(g * 16 + n) * 512 + m0 + t * 16 + q * 4 + i] = hv4[i];
      }
    }

    asm volatile("s_waitcnt vmcnt(0)" ::: "memory");  // own exch stores drained to L2
    __syncthreads();                                   // all waves' stores drained + LDS visible

    if (s < 511) {
      if (tid == 0)
        __hip_atomic_store(&flags[cu * 8], s + 1, __ATOMIC_RELEASE,
                           __HIP_MEMORY_SCOPE_AGENT);  // wbl2 + flag: h_{s+1} published
      xrow += 64 * 512;                                // prefetch next step's x
      xv[0] = *(const short4_t*)&xrow[q * 4];
      xv[1] = *(const short4_t*)&xrow[16 + q * 4];
    }
  }
}

// ---------- kernel C: sig[b] + copy hidden out. 64 blocks x 64 lanes ----------
__global__ __launch_bounds__(64) void kfin(const float* __restrict__ hid,  // [64][512] (in xp)
                                           const float* __restrict__ Wf,   // [512]
                                           const float* __restrict__ bfp,  // [1]
                                           float* __restrict__ out) {      // d_out
  const int b = blockIdx.x, l = threadIdx.x;
  float4 ha = *(const float4*)&hid[b * 512 + l * 4];
  float4 hb = *(const float4*)&hid[b * 512 + 256 + l * 4];
  float4 wa = *(const float4*)&Wf[l * 4];
  float4 wb = *(const float4*)&Wf[256 + l * 4];
  float p = ha.x * wa.x + ha.y * wa.y + ha.z * wa.z + ha.w * wa.w +
            hb.x * wb.x + hb.y * wb.y + hb.z * wb.z + hb.w * wb.w;
  #pragma unroll
  for (int off = 32; off > 0; off >>= 1) p += __shfl_down(p, off, 64);
  *(float4*)&out[64 + b * 512 + l * 4] = ha;        // overwrite exch region w/ hidden
  *(float4*)&out[64 + b * 512 + 256 + l * 4] = hb;
  if (l == 0) out[b] = 1.f / (1.f + __expf(-(p + bfp[0])));  // overwrites flag region
}

extern "C" void kernel_launch(void* const* d_in, const int* in_sizes, int n_in,
                              void* d_out, int out_size, void* d_ws, size_t ws_size,
                              hipStream_t stream) {
  const int*   ids = (const int*)d_in[0];
  const float* emb = (const float*)d_in[1];
  const float* Wh  = (const float*)d_in[2];
  const float* bh  = (const float*)d_in[3];
  const float* Wi  = (const float*)d_in[4];
  const float* bi  = (const float*)d_in[5];
  const float* Wf  = (const float*)d_in[6];
  const float* bf_ = (const float*)d_in[7];
  float* out = (float*)d_out;

  short* xp  = (short*)d_ws;                              // [512][64][512] bf16 = 32 MiB
  short* Whb = (short*)((char*)d_ws + (size_t)33554432);  // [512][512] bf16 = 512 KiB
  (void)in_sizes; (void)n_in; (void)out_size; (void)ws_size;

  kcvt  <<<256, 256, 0, stream>>>(Wh, Whb);
  kxproj<<<dim3(512, 2), 256, 0, stream>>>(ids, emb, Wi, bi, bh, xp);
  krnn  <<<16, 512, 0, stream>>>(Whb, xp, (int*)d_out, (short*)(out + 64));
  kfin  <<<64, 64, 0, stream>>>((const float*)xp, Wf, bf_, out);
}

// Round 7
// 2518.348 us; speedup vs baseline: 2.0553x; 2.0553x over previous
//
#include <hip/hip_runtime.h>
#include <hip/hip_bf16.h>

// ---------- types ----------
typedef __attribute__((ext_vector_type(8))) short short8;   // 8 bf16 = 4 VGPRs (MFMA A/B frag)
typedef __attribute__((ext_vector_type(4))) short short4_t; // 4 bf16
typedef __attribute__((ext_vector_type(4))) float f32x4;    // MFMA C/D frag

__device__ __forceinline__ short f2bf(float x) {
  unsigned int u = __builtin_bit_cast(unsigned int, x);
  unsigned int r = (u + 0x7fffu + ((u >> 16) & 1u)) >> 16;
  return (short)r;
}
__device__ __forceinline__ float bf2f(unsigned short u) {
  unsigned int i = ((unsigned int)u) << 16;
  return __builtin_bit_cast(float, i);
}

// packed f32x2 -> bf16x2 as an int (hardware cvt if available; safe fallback)
__device__ __forceinline__ int pkcvt(float a, float b) {
#if __has_builtin(__builtin_amdgcn_cvt_pk_bf16_f32)
  typedef __attribute__((ext_vector_type(2))) __bf16 bf16x2_t;
  bf16x2_t r = __builtin_amdgcn_cvt_pk_bf16_f32(a, b);
  return __builtin_bit_cast(int, r);
#else
  unsigned int lo = (unsigned short)f2bf(a);
  unsigned int hi = (unsigned short)f2bf(b);
  return (int)(lo | (hi << 16));
#endif
}

#define HROW 520    // shorts per LDS row (1040 B: 16B-aligned)

// lgkmcnt-only barrier (no vmcnt drain — global prefetches stay in flight)
#define LDS_BARRIER() asm volatile("s_waitcnt lgkmcnt(0)\n\ts_barrier" ::: "memory")

// ---------- kernel W: convert Wh fp32 -> bf16 ----------
__global__ __launch_bounds__(256) void kcvt(const float* __restrict__ Wh,
                                            short* __restrict__ Whb) {
  int i = blockIdx.x * 256 + threadIdx.x;          // 65536 float4 groups
  float4 v = ((const float4*)Wh)[i];
  short4_t o;
  o[0] = f2bf(v.x); o[1] = f2bf(v.y); o[2] = f2bf(v.z); o[3] = f2bf(v.w);
  ((short4_t*)Whb)[i] = o;
}

// ---------- kernel A: xp[s][b][h] = sum_e emb[ids[b][s]][e]*Wi[h][e] + bi[h] + bh[h] (bf16) ----------
__global__ __launch_bounds__(256) void kxproj(const int* __restrict__ ids,    // [B=64][S=512]
                                              const float* __restrict__ emb,  // [V][256]
                                              const float* __restrict__ Wi,   // [512][256]
                                              const float* __restrict__ bi,   // [512]
                                              const float* __restrict__ bh,   // [512]
                                              short* __restrict__ xp) {       // [S][64][512] bf16
  const int s  = blockIdx.x;       // 0..511
  const int hb = blockIdx.y;       // 0..1  (h-block of 256)
  __shared__ __align__(16) char smem[42240];
  float* emb_t = (float*)smem;              // [32][68]  = 8704 B
  float* wi_t  = (float*)(smem + 8704);     // [32][260] = 33280 B
  short* stage = (short*)smem;              // [64][264] = 33792 B (phase 2)
  __shared__ int ids_s[64];
  const int tid = threadIdx.x;
  const int b0 = (tid & 7) * 8;
  const int h0 = (tid >> 3) * 8;

  if (tid < 64) ids_s[tid] = ids[tid * 512 + s];
  __syncthreads();

  float acc[8][8];
  #pragma unroll
  for (int i = 0; i < 8; ++i)
    #pragma unroll
    for (int j = 0; j < 8; ++j) acc[i][j] = 0.f;

  for (int ec = 0; ec < 256; ec += 32) {
    #pragma unroll
    for (int j = 0; j < 8; ++j) {
      int idx = j * 256 + tid;
      int e = idx & 31, b = idx >> 5;
      emb_t[e * 68 + b] = emb[ids_s[b] * 256 + ec + e];
    }
    #pragma unroll
    for (int j = 0; j < 8; ++j) {
      int idx4 = j * 256 + tid;
      int e4 = (idx4 & 7) * 4, hl = idx4 >> 3;
      float4 f = *(const float4*)&Wi[(hb * 256 + hl) * 256 + ec + e4];
      wi_t[(e4 + 0) * 260 + hl] = f.x;
      wi_t[(e4 + 1) * 260 + hl] = f.y;
      wi_t[(e4 + 2) * 260 + hl] = f.z;
      wi_t[(e4 + 3) * 260 + hl] = f.w;
    }
    __syncthreads();
    for (int e = 0; e < 32; ++e) {
      const float4 eb0 = *(const float4*)&emb_t[e * 68 + b0];
      const float4 eb1 = *(const float4*)&emb_t[e * 68 + b0 + 4];
      const float4 w0  = *(const float4*)&wi_t[e * 260 + h0];
      const float4 w1  = *(const float4*)&wi_t[e * 260 + h0 + 4];
      float av[8] = {eb0.x, eb0.y, eb0.z, eb0.w, eb1.x, eb1.y, eb1.z, eb1.w};
      float wv[8] = {w0.x, w0.y, w0.z, w0.w, w1.x, w1.y, w1.z, w1.w};
      #pragma unroll
      for (int i = 0; i < 8; ++i)
        #pragma unroll
        for (int j = 0; j < 8; ++j) acc[i][j] += av[i] * wv[j];
    }
    __syncthreads();
  }
  float add[8];
  #pragma unroll
  for (int hj = 0; hj < 8; ++hj) { int h = hb * 256 + h0 + hj; add[hj] = bi[h] + bh[h]; }
  #pragma unroll
  for (int b2 = 0; b2 < 8; ++b2) {
    short8 pk;
    #pragma unroll
    for (int hj = 0; hj < 8; ++hj) pk[hj] = f2bf(acc[b2][hj] + add[hj]);
    *(short8*)&stage[(b0 + b2) * 264 + h0] = pk;
  }
  __syncthreads();
  {
    int n = tid >> 2, ch = tid & 3;
    const short* src = &stage[n * 264 + ch * 64];
    short* dst = &xp[((size_t)s * 64 + n) * 512 + hb * 256 + ch * 64];
    #pragma unroll
    for (int j = 0; j < 8; ++j) *(short8*)&dst[j * 8] = *(const short8*)&src[j * 8];
  }
}

// ---------- kernel B: the recurrence. 4 WGs x 16 batches, 8 waves (2/SIMD). ----------
// Wave w owns rows [64w, 64w+64): tiles 0..2 register-resident (192 regs),
// tile 3 STREAMED from L2 每 step via a rolling 4-slot register buffer
// (16 VGPRs; slot kt&3 reloaded right after its MFMA use, landing 4 kt later
// — ~300 cyc of cover vs ~200 cyc L2 latency). This moves 128 KB/step of
// constant-Wh traffic off the saturated DS pipe onto the idle VMEM pipe.
// h state (16 batches x 512 bf16) in LDS. Barriers are lgkmcnt-only.
__global__ __launch_bounds__(512, 2) void krnn(const short* __restrict__ Whb, // [512][512] bf16
                                               const short* __restrict__ xp,  // [S][64][512] bf16
                                               float* __restrict__ d_out) {
  __shared__ short h_lds[16 * HROW];        // 16,640 B (only LDS now)
  const int tid = threadIdx.x;
  const int w   = tid >> 6;       // wave 0..7
  const int l   = tid & 63;
  const int n   = l & 15;         // MFMA col / batch-in-group / A-row-in-tile
  const int q   = l >> 4;         // quad 0..3
  const int g   = blockIdx.x;     // batch group 0..3
  const int m0  = w * 64;

  for (int i = tid; i < 16 * HROW / 2; i += 512) ((int*)h_lds)[i] = 0;

  // register A-frags, tiles 0..2: A[m = n][k = q*8+j]
  short8 areg[3][16];
  #pragma unroll
  for (int t = 0; t < 3; ++t) {
    const short* base = &Whb[(m0 + t * 16 + n) * 512 + q * 8];
    #pragma unroll
    for (int kt = 0; kt < 16; ++kt) areg[t][kt] = *(const short8*)&base[kt * 32];
  }
  __syncthreads();

  // tile-3 stream base (row m0+48+n, frag col q*8) — values identical every
  // step; asm obfuscation below keeps the loads inside the s-loop without
  // letting the compiler hoist 64 regs worth of "loop-invariant" loads.
  const short* a3p = &Whb[(m0 + 48 + n) * 512 + q * 8];

  // prime rolling buffer with kt = 0..3
  short8 c3buf[4];
  #pragma unroll
  for (int j = 0; j < 4; ++j) c3buf[j] = *(const short8*)&a3p[j * 32];

  // x for current step: 4 short4 chunks (t tiles, q offset)
  const short* xrow = &xp[(size_t)(g * 16 + n) * 512 + m0];
  short4_t xv[4];
  #pragma unroll
  for (int t = 0; t < 4; ++t) xv[t] = *(const short4_t*)&xrow[t * 16 + q * 4];

  for (int s = 0; s < 512; ++s) {
    asm volatile("" : "+v"(a3p));   // make a3p opaque per step (no hoisting)

    f32x4 acc[4];
    #pragma unroll
    for (int t = 0; t < 4; ++t) acc[t] = (f32x4){0.f, 0.f, 0.f, 0.f};

    #pragma unroll
    for (int kt = 0; kt < 16; ++kt) {
      short8 bfrag = *(const short8*)&h_lds[n * HROW + kt * 32 + q * 8];
      acc[0] = __builtin_amdgcn_mfma_f32_16x16x32_bf16(areg[0][kt], bfrag, acc[0], 0, 0, 0);
      acc[1] = __builtin_amdgcn_mfma_f32_16x16x32_bf16(areg[1][kt], bfrag, acc[1], 0, 0, 0);
      acc[2] = __builtin_amdgcn_mfma_f32_16x16x32_bf16(areg[2][kt], bfrag, acc[2], 0, 0, 0);
      acc[3] = __builtin_amdgcn_mfma_f32_16x16x32_bf16(c3buf[kt & 3], bfrag, acc[3], 0, 0, 0);
      // reload this slot for kt+4 (wraps into next step's kt 0..3)
      c3buf[kt & 3] = *(const short8*)&a3p[((kt + 4) & 15) * 32];
    }
    LDS_BARRIER();   // all waves' h reads done (lgkm only; VMEM stays in flight)

    // epilogue: z = Wh.h + x, h' = sigmoid(z); write back [n][k]
    #pragma unroll
    for (int t = 0; t < 4; ++t) {
      float hv4[4];
      #pragma unroll
      for (int i = 0; i < 4; ++i) {
        float z = acc[t][i] + bf2f((unsigned short)xv[t][i]);
        float e = __expf(-z);
        hv4[i] = __builtin_amdgcn_rcpf(1.f + e);
      }
      int2 hpk;
      hpk.x = pkcvt(hv4[0], hv4[1]);
      hpk.y = pkcvt(hv4[2], hv4[3]);
      if (s == 511) {
        #pragma unroll
        for (int i = 0; i < 4; ++i) {
          int m = m0 + t * 16 + q * 4 + i;
          d_out[64 + (g * 16 + n) * 512 + m] = hv4[i];
        }
      }
      *(short4_t*)&h_lds[n * HROW + m0 + t * 16 + q * 4] = __builtin_bit_cast(short4_t, hpk);
    }

    // prefetch next step's x (consumed regs now free)
    xrow += 64 * 512;
    if (s < 511) {
      #pragma unroll
      for (int t = 0; t < 4; ++t) xv[t] = *(const short4_t*)&xrow[t * 16 + q * 4];
    }

    LDS_BARRIER();   // h' visible to all waves
  }
}

// ---------- kernel C: sig[b] = sigmoid(hidden[b] . Wf + bf) ----------
__global__ __launch_bounds__(256) void kfin(const float* __restrict__ hid,  // d_out+64, [64][512]
                                            const float* __restrict__ Wf,   // [512]
                                            const float* __restrict__ bfp,  // [1]
                                            float* __restrict__ out) {
  __shared__ float red[4][64];
  int t = threadIdx.x, b = t & 63, qq = t >> 6;
  const float4* hv = (const float4*)&hid[b * 512 + qq * 128];
  const float4* wv = (const float4*)&Wf[qq * 128];
  float p = 0.f;
  #pragma unroll 8
  for (int k = 0; k < 32; ++k) {
    float4 hx = hv[k]; float4 wx = wv[k];
    p += hx.x * wx.x + hx.y * wx.y + hx.z * wx.z + hx.w * wx.w;
  }
  red[qq][b] = p;
  __syncthreads();
  if (t < 64) {
    float z = red[0][t] + red[1][t] + red[2][t] + red[3][t] + bfp[0];
    out[t] = 1.f / (1.f + __expf(-z));
  }
}

extern "C" void kernel_launch(void* const* d_in, const int* in_sizes, int n_in,
                              void* d_out, int out_size, void* d_ws, size_t ws_size,
                              hipStream_t stream) {
  const int*   ids = (const int*)d_in[0];
  const float* emb = (const float*)d_in[1];
  const float* Wh  = (const float*)d_in[2];
  const float* bh  = (const float*)d_in[3];
  const float* Wi  = (const float*)d_in[4];
  const float* bi  = (const float*)d_in[5];
  const float* Wf  = (const float*)d_in[6];
  const float* bf_ = (const float*)d_in[7];
  float* out = (float*)d_out;

  short* xp  = (short*)d_ws;                              // [512][64][512] bf16 = 32 MiB
  short* Whb = (short*)((char*)d_ws + (size_t)33554432);  // [512][512] bf16 = 512 KiB
  (void)in_sizes; (void)n_in; (void)out_size; (void)ws_size;

  kcvt  <<<256, 256, 0, stream>>>(Wh, Whb);
  kxproj<<<dim3(512, 2), 256, 0, stream>>>(ids, emb, Wi, bi, bh, xp);
  krnn  <<<4, 512, 0, stream>>>(Whb, xp, out);
  kfin  <<<1, 256, 0, stream>>>(out + 64, Wf, bf_, out);
}

// Round 9
// 913.079 us; speedup vs baseline: 5.6686x; 2.7581x over previous
//
#include <hip/hip_runtime.h>
#include <hip/hip_bf16.h>

// ---------- types ----------
typedef __attribute__((ext_vector_type(8))) short short8;   // 8 bf16 = 4 VGPRs (MFMA A/B frag)
typedef __attribute__((ext_vector_type(4))) short short4_t; // 4 bf16
typedef __attribute__((ext_vector_type(4))) float f32x4;    // MFMA C/D frag

__device__ __forceinline__ short f2bf(float x) {
  unsigned int u = __builtin_bit_cast(unsigned int, x);
  unsigned int r = (u + 0x7fffu + ((u >> 16) & 1u)) >> 16;
  return (short)r;
}
__device__ __forceinline__ float bf2f(unsigned short u) {
  unsigned int i = ((unsigned int)u) << 16;
  return __builtin_bit_cast(float, i);
}

// packed f32x2 -> bf16x2 as an int (hardware cvt if available; safe fallback)
__device__ __forceinline__ int pkcvt(float a, float b) {
#if __has_builtin(__builtin_amdgcn_cvt_pk_bf16_f32)
  typedef __attribute__((ext_vector_type(2))) __bf16 bf16x2_t;
  bf16x2_t r = __builtin_amdgcn_cvt_pk_bf16_f32(a, b);
  return __builtin_bit_cast(int, r);
#else
  unsigned int lo = (unsigned short)f2bf(a);
  unsigned int hi = (unsigned short)f2bf(b);
  return (int)(lo | (hi << 16));
#endif
}

// lgkmcnt-only barrier (no vmcnt drain — global prefetches stay in flight)
#define LDS_BARRIER() asm volatile("s_waitcnt lgkmcnt(0)\n\ts_barrier" ::: "memory")

// ---------- kernel W: convert Wh and Wi fp32 -> bf16 ----------
__global__ __launch_bounds__(256) void kcvt(const float* __restrict__ Wh,
                                            const float* __restrict__ Wi,
                                            short* __restrict__ Whb,
                                            short* __restrict__ Wib) {
  int i = blockIdx.x * 256 + threadIdx.x;   // 0..98303 float4 groups
  const float4* src; short4_t* dst; int j;
  if (i < 65536) { src = (const float4*)Wh; dst = (short4_t*)Whb; j = i; }
  else           { src = (const float4*)Wi; dst = (short4_t*)Wib; j = i - 65536; }
  float4 v = src[j];
  short4_t o;
  o[0] = f2bf(v.x); o[1] = f2bf(v.y); o[2] = f2bf(v.z); o[3] = f2bf(v.w);
  dst[j] = o;
}

// ---------- kernel A (MFMA): xp[s][b][h] = sum_e emb[ids[b][s]][e]*Wi[h][e] + bi[h] + bh[h] ----------
// One block per s. 8 waves; wave w owns h range [64w, 64w+64) (4 N-tiles).
// A = emb rows (bf16, staged in LDS), B = Wib rows (bf16, straight from L2).
__global__ __launch_bounds__(512, 2) void kxproj(const int* __restrict__ ids,    // [B=64][S=512]
                                                 const float* __restrict__ emb,  // [V][256] fp32
                                                 const short* __restrict__ Wib,  // [512][256] bf16
                                                 const float* __restrict__ bi,   // [512]
                                                 const float* __restrict__ bh,   // [512]
                                                 short* __restrict__ xp) {       // [S][64][512] bf16
  const int s = blockIdx.x;
  __shared__ short E[64 * 264];   // [b][e] bf16, row stride 264 shorts (528 B)
  __shared__ float bias[512];
  __shared__ int ids_s[64];
  const int tid = threadIdx.x;    // 0..511
  const int w = tid >> 6, l = tid & 63, n = l & 15, q = l >> 4;

  if (tid < 64) ids_s[tid] = ids[tid * 512 + s];
  if (tid < 256) {
    bias[tid]       = bi[tid]       + bh[tid];
    bias[tid + 256] = bi[tid + 256] + bh[tid + 256];
  }
  __syncthreads();

  // stage emb rows -> bf16 LDS: thread t handles row t>>3, 32-e chunk (t&7)
  {
    const int row = tid >> 3, part = tid & 7;
    const float* src = &emb[(size_t)ids_s[row] * 256 + part * 32];
    short* dst = &E[row * 264 + part * 32];
    #pragma unroll
    for (int j = 0; j < 8; ++j) {
      float4 v = ((const float4*)src)[j];
      int2 pk;
      pk.x = pkcvt(v.x, v.y);
      pk.y = pkcvt(v.z, v.w);
      *(int2*)&dst[j * 4] = pk;
    }
  }
  __syncthreads();

  // GEMM: M=64 (batches), N=64 per wave, K=256
  f32x4 acc[4][4];   // [mt][nt]
  #pragma unroll
  for (int mt = 0; mt < 4; ++mt)
    #pragma unroll
    for (int nt = 0; nt < 4; ++nt) acc[mt][nt] = (f32x4){0.f, 0.f, 0.f, 0.f};

  const short* bbase = &Wib[(size_t)(w * 64 + n) * 256 + q * 8];
  #pragma unroll
  for (int kt = 0; kt < 8; ++kt) {
    short8 afrag[4];
    #pragma unroll
    for (int mt = 0; mt < 4; ++mt)
      afrag[mt] = *(const short8*)&E[(mt * 16 + n) * 264 + kt * 32 + q * 8];
    #pragma unroll
    for (int nt = 0; nt < 4; ++nt) {
      short8 bfrag = *(const short8*)&bbase[nt * 16 * 256 + kt * 32];
      #pragma unroll
      for (int mt = 0; mt < 4; ++mt)
        acc[mt][nt] = __builtin_amdgcn_mfma_f32_16x16x32_bf16(afrag[mt], bfrag, acc[mt][nt], 0, 0, 0);
    }
  }

  // epilogue: + bias, cvt bf16, store
  #pragma unroll
  for (int nt = 0; nt < 4; ++nt) {
    float bv = bias[w * 64 + nt * 16 + n];
    #pragma unroll
    for (int mt = 0; mt < 4; ++mt) {
      #pragma unroll
      for (int i = 0; i < 4; ++i) {
        short sv = f2bf(acc[mt][nt][i] + bv);
        xp[((size_t)s * 64 + mt * 16 + q * 4 + i) * 512 + w * 64 + nt * 16 + n] = sv;
      }
    }
  }
}

// ---------- kernel B: the recurrence. 4 WGs x 16 batches, 8 waves (2/SIMD). ----------
// SWIZZLED LDS layouts (fragment-major): element (batch n, k) of h lives at
//   h_lds[buf][ (k>>5)*1024B + (((k&31)>>3)*16 + n)*16B + (k&7)*2B ]
// so the per-kt B-frag read is ds_read_b128 at kt*1024 + lane*16 — linear,
// conflict-free, no padding. Same swizzle for the LDS-resident Wh tile
// (blocks kt=0..14; kt=15 lives in one extra register frag). h is double-
// buffered -> ONE lgkm-barrier per step. Tiles 0..2 register-resident.
__global__ __launch_bounds__(512, 2) void krnn(const short* __restrict__ Whb, // [512][512] bf16
                                               const short* __restrict__ xp,  // [S][64][512] bf16
                                               float* __restrict__ d_out) {
  __shared__ short h_lds[2][16 * 512];      // 2 x 16,384 B (swizzled)
  __shared__ short a_lds[8][15 * 512];      // 8 waves x 15 kt-blocks: 122,880 B
  const int tid = threadIdx.x;
  const int w   = tid >> 6;       // wave 0..7
  const int l   = tid & 63;
  const int n   = l & 15;         // MFMA col / batch-in-group / A-row-in-tile
  const int q   = l >> 4;         // quad 0..3
  const int g   = blockIdx.x;     // batch group 0..3
  const int m0  = w * 64;

  // zero h buf 0 (read at s=0)
  for (int i = tid; i < 16 * 512 / 2; i += 512) ((int*)h_lds[0])[i] = 0;

  // preload swizzled LDS A tile (kt 0..14) + keep kt=15 frag in registers
  const short* a3src = &Whb[(m0 + 48 + n) * 512 + q * 8];
  for (int kt = 0; kt < 15; ++kt)
    *(short8*)&a_lds[w][kt * 512 + l * 8] = *(const short8*)&a3src[kt * 32];
  short8 a3_15 = *(const short8*)&a3src[15 * 32];

  // register A-frags, tiles 0..2: A[m = n][k = q*8+j]
  short8 areg[3][16];
  #pragma unroll
  for (int t = 0; t < 3; ++t) {
    const short* base = &Whb[(m0 + t * 16 + n) * 512 + q * 8];
    #pragma unroll
    for (int kt = 0; kt < 16; ++kt) areg[t][kt] = *(const short8*)&base[kt * 32];
  }
  __syncthreads();

  const short* a3l = &a_lds[w][l * 8];

  // x for current step: 4 short4 chunks (t tiles, q offset)
  const short* xrow = &xp[(size_t)(g * 16 + n) * 512 + m0];
  short4_t xv[4];
  #pragma unroll
  for (int t = 0; t < 4; ++t) xv[t] = *(const short4_t*)&xrow[t * 16 + q * 4];

  for (int s = 0; s < 512; ++s) {
    const short* rb = h_lds[s & 1];
    short*       wb = h_lds[1 - (s & 1)];

    f32x4 acc[4];
    #pragma unroll
    for (int t = 0; t < 4; ++t) acc[t] = (f32x4){0.f, 0.f, 0.f, 0.f};

    #pragma unroll
    for (int kt = 0; kt < 16; ++kt) {
      short8 bfrag = *(const short8*)&rb[kt * 512 + l * 8];     // linear, conflict-free
      short8 a3 = (kt < 15) ? *(const short8*)&a3l[kt * 512] : a3_15;
      acc[0] = __builtin_amdgcn_mfma_f32_16x16x32_bf16(areg[0][kt], bfrag, acc[0], 0, 0, 0);
      acc[1] = __builtin_amdgcn_mfma_f32_16x16x32_bf16(areg[1][kt], bfrag, acc[1], 0, 0, 0);
      acc[2] = __builtin_amdgcn_mfma_f32_16x16x32_bf16(areg[2][kt], bfrag, acc[2], 0, 0, 0);
      acc[3] = __builtin_amdgcn_mfma_f32_16x16x32_bf16(a3,          bfrag, acc[3], 0, 0, 0);
    }
    // no barrier here: reads hit rb, writes go to wb (disjoint buffers)

    // epilogue: z = Wh.h + x, h' = sigmoid(z); write into wb (swizzled)
    #pragma unroll
    for (int t = 0; t < 4; ++t) {
      float hv4[4];
      #pragma unroll
      for (int i = 0; i < 4; ++i) {
        float z = acc[t][i] + bf2f((unsigned short)xv[t][i]);
        float e = __expf(-z);
        hv4[i] = __builtin_amdgcn_rcpf(1.f + e);
      }
      int2 hpk;
      hpk.x = pkcvt(hv4[0], hv4[1]);
      hpk.y = pkcvt(hv4[2], hv4[3]);
      if (s == 511) {
        #pragma unroll
        for (int i = 0; i < 4; ++i) {
          int m = m0 + t * 16 + q * 4 + i;
          d_out[64 + (g * 16 + n) * 512 + m] = hv4[i];
        }
      }
      // k = m0 + t*16 + q*4 + i  ->  swizzled addr
      int ktw   = 2 * w + (t >> 1);
      int laneW = ((t & 1) * 2 + (q >> 1)) * 16 + n;
      *(short4_t*)&wb[ktw * 512 + laneW * 8 + (q & 1) * 4] =
          __builtin_bit_cast(short4_t, hpk);
    }

    // prefetch next step's x (consumed regs now free)
    xrow += 64 * 512;
    if (s < 511) {
      #pragma unroll
      for (int t = 0; t < 4; ++t) xv[t] = *(const short4_t*)&xrow[t * 16 + q * 4];
    }

    LDS_BARRIER();   // single barrier: wb complete & visible before next step reads it
  }
}

// ---------- kernel C: sig[b] = sigmoid(hidden[b] . Wf + bf) ----------
__global__ __launch_bounds__(256) void kfin(const float* __restrict__ hid,  // d_out+64, [64][512]
                                            const float* __restrict__ Wf,   // [512]
                                            const float* __restrict__ bfp,  // [1]
                                            float* __restrict__ out) {
  __shared__ float red[4][64];
  int t = threadIdx.x, b = t & 63, qq = t >> 6;
  const float4* hv = (const float4*)&hid[b * 512 + qq * 128];
  const float4* wv = (const float4*)&Wf[qq * 128];
  float p = 0.f;
  #pragma unroll 8
  for (int k = 0; k < 32; ++k) {
    float4 hx = hv[k]; float4 wx = wv[k];
    p += hx.x * wx.x + hx.y * wx.y + hx.z * wx.z + hx.w * wx.w;
  }
  red[qq][b] = p;
  __syncthreads();
  if (t < 64) {
    float z = red[0][t] + red[1][t] + red[2][t] + red[3][t] + bfp[0];
    out[t] = 1.f / (1.f + __expf(-z));
  }
}

extern "C" void kernel_launch(void* const* d_in, const int* in_sizes, int n_in,
                              void* d_out, int out_size, void* d_ws, size_t ws_size,
                              hipStream_t stream) {
  const int*   ids = (const int*)d_in[0];
  const float* emb = (const float*)d_in[1];
  const float* Wh  = (const float*)d_in[2];
  const float* bh  = (const float*)d_in[3];
  const float* Wi  = (const float*)d_in[4];
  const float* bi  = (const float*)d_in[5];
  const float* Wf  = (const float*)d_in[6];
  const float* bf_ = (const float*)d_in[7];
  float* out = (float*)d_out;

  short* xp  = (short*)d_ws;                              // [512][64][512] bf16 = 32 MiB
  short* Whb = (short*)((char*)d_ws + (size_t)33554432);  // [512][512] bf16 = 512 KiB
  short* Wib = (short*)((char*)d_ws + (size_t)34078720);  // [512][256] bf16 = 256 KiB
  (void)in_sizes; (void)n_in; (void)out_size; (void)ws_size;

  kcvt  <<<384, 256, 0, stream>>>(Wh, Wi, Whb, Wib);
  kxproj<<<512, 512, 0, stream>>>(ids, emb, Wib, bi, bh, xp);
  krnn  <<<4, 512, 0, stream>>>(Whb, xp, out);
  kfin  <<<1, 256, 0, stream>>>(out + 64, Wf, bf_, out);
}